// Round 1
// baseline (97.920 us; speedup 1.0000x reference)
//
#include <hip/hip_runtime.h>
#include <hip/hip_bf16.h>
#include <stdint.h>

#define M_DIM 2048
#define K_DIM 4096
#define N_DIM 4096

typedef __attribute__((ext_vector_type(8))) short short8;
typedef __attribute__((ext_vector_type(4))) float f32x4;

// RNE float -> bf16, packed pair
__device__ __forceinline__ uint32_t bf16pk(float a, float b) {
  uint32_t ua = __float_as_uint(a);
  ua = (ua + 0x7FFFu + ((ua >> 16) & 1u)) >> 16;
  uint32_t ub = __float_as_uint(b);
  ub = (ub + 0x7FFFu + ((ub >> 16) & 1u)) >> 16;
  return ua | (ub << 16);
}

// ---------------------------------------------------------------------------
// Prepass 1: x fp32 [M][K] -> pre-swizzled bf16 tile images
// xImg[mt][kt][16KB image]:  image byte = m*128 + ((k8*16) ^ ((m&7)*16))
// tile = 128 rows (m) x 64 cols (k), chunk = 8 bf16 = 16B along k.
// ---------------------------------------------------------------------------
__global__ void __launch_bounds__(256) cvt_x_kernel(const float* __restrict__ x,
                                                    uint32_t* __restrict__ xImg) {
  int bid = blockIdx.x;          // 1024 blocks = 16 mt * 64 kt
  int mt = bid >> 6;
  int kt = bid & 63;
  int tid = threadIdx.x;
  uint32_t* tileOut = xImg + (size_t)(mt * 64 + kt) * 4096;
  const float* xbase = x + (size_t)mt * 128 * K_DIM + kt * 64;
#pragma unroll
  for (int i = 0; i < 4; ++i) {
    int o = i * 256 + tid;           // chunk index 0..1023
    int m = o >> 3;
    int slot = o & 7;
    int k8 = slot ^ (m & 7);         // inverse swizzle on source
    const float* src = xbase + (size_t)m * K_DIM + k8 * 8;
    float4 f0 = *(const float4*)(src);
    float4 f1 = *(const float4*)(src + 4);
    uint4 pk;
    pk.x = bf16pk(f0.x, f0.y);
    pk.y = bf16pk(f0.z, f0.w);
    pk.z = bf16pk(f1.x, f1.y);
    pk.w = bf16pk(f1.z, f1.w);
    *(uint4*)(tileOut + (size_t)o * 4) = pk;
  }
}

// ---------------------------------------------------------------------------
// Prepass 2: dequant int4 W -> pre-swizzled bf16 tile images (B^T layout)
// wImg[nt][kt][16KB image]: image byte = n*128 + ((k8*16) ^ ((n&7)*16))
// One qweight int32 = 8 consecutive k for one n = exactly one 16B chunk.
// W[k][n] = (nibble(qweight[k/8][n], k%8) - (nibble(qzeros[g][n/8], n%8)+1)) * scales[g][n]
// g = k/128 (g_idx is arange(K)//128).
// ---------------------------------------------------------------------------
__global__ void __launch_bounds__(256) deq_w_kernel(const uint32_t* __restrict__ qweight,
                                                    const uint32_t* __restrict__ qzeros,
                                                    const float* __restrict__ scales,
                                                    uint32_t* __restrict__ wImg) {
  __shared__ uint32_t img[4096];   // 16 KB tile image
  int bid = blockIdx.x;            // 2048 blocks = 32 nt * 64 kt
  int kt = bid & 63;
  int nt = bid >> 6;
  int tid = threadIdx.x;
  int n = tid & 127;
  int kh = tid >> 7;               // 0..1
  int g = kt >> 1;                 // BK=64, group=128 -> group constant per tile
  int gn = nt * 128 + n;

  uint32_t zq = qzeros[g * (N_DIM / 8) + (gn >> 3)];
  int z = (int)((zq >> ((gn & 7) * 4)) & 15u) + 1;
  float s = scales[g * N_DIM + gn];

#pragma unroll
  for (int j = 0; j < 4; ++j) {
    int k8 = kh * 4 + j;
    uint32_t q = qweight[(size_t)(kt * 8 + k8) * N_DIM + gn];
    float f[8];
#pragma unroll
    for (int v = 0; v < 8; ++v) {
      int w = (int)((q >> (4 * v)) & 15u);
      f[v] = (float)(w - z) * s;   // exact int sub, then cvt+mul (no magic-fma cancellation)
    }
    uint4 pk;
    pk.x = bf16pk(f[0], f[1]);
    pk.y = bf16pk(f[2], f[3]);
    pk.z = bf16pk(f[4], f[5]);
    pk.w = bf16pk(f[6], f[7]);
    int slot = k8 ^ (n & 7);
    *(uint4*)(&img[(n * 8 + slot) * 4]) = pk;
  }
  __syncthreads();
  uint32_t* tileOut = wImg + (size_t)(nt * 64 + kt) * 4096;
#pragma unroll
  for (int i = 0; i < 4; ++i) {
    int o = i * 256 + tid;
    *(uint4*)(tileOut + (size_t)o * 4) = *(const uint4*)(&img[o * 4]);
  }
}

// ---------------------------------------------------------------------------
// GEMM: C = Xbf16 @ Wbf16 + bias.  m97 structure: 128x128 tile, BK=64,
// 4 waves (2x2), 4x4 16x16x32 frags/wave, global_load_lds width 16,
// single-buffer LDS, 2 barriers per K-step. Images are pre-swizzled so
// staging is a linear lane-ordered copy.
// ---------------------------------------------------------------------------
__global__ void __launch_bounds__(256) gemm_kernel(const uint32_t* __restrict__ xImg,
                                                   const uint32_t* __restrict__ wImg,
                                                   const float* __restrict__ bias,
                                                   float* __restrict__ out) {
  __shared__ uint32_t sA[4096];   // 16 KB
  __shared__ uint32_t sB[4096];   // 16 KB
  int bid = blockIdx.x;           // 512 blocks = 16 mb * 32 nb, nb fastest
  int nb = bid & 31;
  int mb = bid >> 5;
  int tid = threadIdx.x;
  int lane = tid & 63;
  int wid = tid >> 6;
  int wr = wid >> 1, wc = wid & 1;
  int lr = lane & 15, lk = lane >> 4;

  f32x4 acc[4][4];
#pragma unroll
  for (int i = 0; i < 4; ++i)
#pragma unroll
    for (int j = 0; j < 4; ++j) acc[i][j] = f32x4{0.f, 0.f, 0.f, 0.f};

  const char* aTile = (const char*)(xImg + (size_t)mb * 64 * 4096);
  const char* bTile = (const char*)(wImg + (size_t)nb * 64 * 4096);

  int swz = (lr & 7) << 4;
  int rowA[4], rowB[4];
#pragma unroll
  for (int i = 0; i < 4; ++i) rowA[i] = (wr * 64 + i * 16 + lr) * 128;
#pragma unroll
  for (int j = 0; j < 4; ++j) rowB[j] = (wc * 64 + j * 16 + lr) * 128;

  for (int kt = 0; kt < 64; ++kt) {
#pragma unroll
    for (int s2 = 0; s2 < 4; ++s2) {
      int c = wid * 4 + s2;                 // 16 chunks of 1KB cover the 16KB image
      int off = c * 1024 + lane * 16;       // per-lane global source
      __builtin_amdgcn_global_load_lds(
          (__attribute__((address_space(1))) void*)(aTile + off),
          (__attribute__((address_space(3))) void*)((char*)sA + c * 1024), 16, 0, 0);
      __builtin_amdgcn_global_load_lds(
          (__attribute__((address_space(1))) void*)(bTile + off),
          (__attribute__((address_space(3))) void*)((char*)sB + c * 1024), 16, 0, 0);
    }
    __syncthreads();   // drains vmcnt: staged data visible
#pragma unroll
    for (int ks = 0; ks < 2; ++ks) {
      int kb = ks * 64 + lk * 16;
      int ko = kb ^ swz;
      short8 af[4], bf[4];
#pragma unroll
      for (int i = 0; i < 4; ++i)
        af[i] = *(const short8*)((const char*)sA + rowA[i] + ko);
#pragma unroll
      for (int j = 0; j < 4; ++j)
        bf[j] = *(const short8*)((const char*)sB + rowB[j] + ko);
#pragma unroll
      for (int i = 0; i < 4; ++i)
#pragma unroll
        for (int j = 0; j < 4; ++j)
          acc[i][j] = __builtin_amdgcn_mfma_f32_16x16x32_bf16(af[i], bf[j], acc[i][j], 0, 0, 0);
    }
    __syncthreads();   // all waves done reading before next stage overwrites
    aTile += 16384;
    bTile += 16384;
  }

  // epilogue: C/D mapping col=lane&15, row=(lane>>4)*4+reg (m89-verified)
  int colBase = nb * 128 + wc * 64 + lr;
  int rowBase = mb * 128 + wr * 64 + lk * 4;
#pragma unroll
  for (int j = 0; j < 4; ++j) {
    int col = colBase + j * 16;
    float bj = bias[col];
#pragma unroll
    for (int i = 0; i < 4; ++i) {
      int row = rowBase + i * 16;
#pragma unroll
      for (int r = 0; r < 4; ++r) {
        out[(size_t)(row + r) * N_DIM + col] = acc[i][j][r] + bj;
      }
    }
  }
}

// ---------------------------------------------------------------------------
// Fallback (workspace too small): correct-but-slow fp32 tiled GEMM w/ fused dequant
// ---------------------------------------------------------------------------
__global__ void fallback_kernel(const float* __restrict__ x, const uint32_t* __restrict__ qweight,
                                const uint32_t* __restrict__ qzeros, const float* __restrict__ scales,
                                const float* __restrict__ bias, float* __restrict__ out) {
  __shared__ float xs[16][17];
  __shared__ float ws[16][17];
  int tx = threadIdx.x, ty = threadIdx.y;
  int col = blockIdx.x * 16 + tx;
  int row = blockIdx.y * 16 + ty;
  float acc = 0.f;
  for (int k0 = 0; k0 < K_DIM; k0 += 16) {
    xs[ty][tx] = x[(size_t)row * K_DIM + k0 + tx];
    int k = k0 + ty;
    int g = k >> 7;
    uint32_t q = qweight[(size_t)(k >> 3) * N_DIM + col];
    int w = (int)((q >> ((k & 7) * 4)) & 15u);
    uint32_t zq = qzeros[g * (N_DIM / 8) + (col >> 3)];
    int z = (int)((zq >> ((col & 7) * 4)) & 15u) + 1;
    ws[ty][tx] = (float)(w - z) * scales[g * N_DIM + col];
    __syncthreads();
#pragma unroll
    for (int kk = 0; kk < 16; ++kk) acc += xs[ty][kk] * ws[kk][tx];
    __syncthreads();
  }
  out[(size_t)row * N_DIM + col] = acc + bias[col];
}

extern "C" void kernel_launch(void* const* d_in, const int* in_sizes, int n_in,
                              void* d_out, int out_size, void* d_ws, size_t ws_size,
                              hipStream_t stream) {
  const float* x = (const float*)d_in[0];
  const uint32_t* qweight = (const uint32_t*)d_in[1];
  const uint32_t* qzeros = (const uint32_t*)d_in[2];
  const float* scales = (const float*)d_in[3];
  // d_in[4] = g_idx (== arange(K)//128, folded into index math)
  const float* bias = (const float*)d_in[5];
  float* out = (float*)d_out;

  const size_t X_IMG_BYTES = (size_t)16 * 64 * 16384;   // 16.78 MB
  const size_t W_IMG_BYTES = (size_t)32 * 64 * 16384;   // 33.55 MB

  if (ws_size >= X_IMG_BYTES + W_IMG_BYTES) {
    uint32_t* xImg = (uint32_t*)d_ws;
    uint32_t* wImg = (uint32_t*)((char*)d_ws + X_IMG_BYTES);
    cvt_x_kernel<<<1024, 256, 0, stream>>>(x, xImg);
    deq_w_kernel<<<2048, 256, 0, stream>>>(qweight, qzeros, scales, wImg);
    gemm_kernel<<<512, 256, 0, stream>>>(xImg, wImg, bias, out);
  } else {
    fallback_kernel<<<dim3(N_DIM / 16, M_DIM / 16), dim3(16, 16), 0, stream>>>(
        x, qweight, qzeros, scales, bias, out);
  }
}

// Round 2
// 87.354 us; speedup vs baseline: 1.1210x; 1.1210x over previous
//
#include <hip/hip_runtime.h>
#include <hip/hip_bf16.h>
#include <stdint.h>

#define M_DIM 2048
#define K_DIM 4096
#define N_DIM 4096

typedef __attribute__((ext_vector_type(8))) short short8;
typedef __attribute__((ext_vector_type(4))) float f32x4;

// RNE float -> bf16, packed pair
__device__ __forceinline__ uint32_t bf16pk(float a, float b) {
  uint32_t ua = __float_as_uint(a);
  ua = (ua + 0x7FFFu + ((ua >> 16) & 1u)) >> 16;
  uint32_t ub = __float_as_uint(b);
  ub = (ub + 0x7FFFu + ((ub >> 16) & 1u)) >> 16;
  return ua | (ub << 16);
}

// ---------------------------------------------------------------------------
// Prepass 1: x fp32 [M][K] -> pre-swizzled bf16 tile images
// xImg[mt][kt][16KB image]:  image byte = m*128 + ((k8*16) ^ ((m&7)*16))
// ---------------------------------------------------------------------------
__global__ void __launch_bounds__(256) cvt_x_kernel(const float* __restrict__ x,
                                                    uint32_t* __restrict__ xImg) {
  int bid = blockIdx.x;          // 1024 blocks = 16 mt * 64 kt
  int mt = bid >> 6;
  int kt = bid & 63;
  int tid = threadIdx.x;
  uint32_t* tileOut = xImg + (size_t)(mt * 64 + kt) * 4096;
  const float* xbase = x + (size_t)mt * 128 * K_DIM + kt * 64;
#pragma unroll
  for (int i = 0; i < 4; ++i) {
    int o = i * 256 + tid;           // chunk index 0..1023
    int m = o >> 3;
    int slot = o & 7;
    int k8 = slot ^ (m & 7);         // inverse swizzle on source
    const float* src = xbase + (size_t)m * K_DIM + k8 * 8;
    float4 f0 = *(const float4*)(src);
    float4 f1 = *(const float4*)(src + 4);
    uint4 pk;
    pk.x = bf16pk(f0.x, f0.y);
    pk.y = bf16pk(f0.z, f0.w);
    pk.z = bf16pk(f1.x, f1.y);
    pk.w = bf16pk(f1.z, f1.w);
    *(uint4*)(tileOut + (size_t)o * 4) = pk;
  }
}

// ---------------------------------------------------------------------------
// Prepass 2: dequant int4 W -> pre-swizzled bf16 tile images (B^T layout)
// wImg[nt][kt][16KB image]: image byte = n*128 + ((k8*16) ^ ((n&7)*16))
// ---------------------------------------------------------------------------
__global__ void __launch_bounds__(256) deq_w_kernel(const uint32_t* __restrict__ qweight,
                                                    const uint32_t* __restrict__ qzeros,
                                                    const float* __restrict__ scales,
                                                    uint32_t* __restrict__ wImg) {
  __shared__ uint32_t img[4096];   // 16 KB tile image
  int bid = blockIdx.x;            // 2048 blocks = 32 nt * 64 kt
  int kt = bid & 63;
  int nt = bid >> 6;
  int tid = threadIdx.x;
  int n = tid & 127;
  int kh = tid >> 7;               // 0..1
  int g = kt >> 1;                 // BK=64, group=128 -> group constant per tile
  int gn = nt * 128 + n;

  uint32_t zq = qzeros[g * (N_DIM / 8) + (gn >> 3)];
  int z = (int)((zq >> ((gn & 7) * 4)) & 15u) + 1;
  float s = scales[g * N_DIM + gn];

#pragma unroll
  for (int j = 0; j < 4; ++j) {
    int k8 = kh * 4 + j;
    uint32_t q = qweight[(size_t)(kt * 8 + k8) * N_DIM + gn];
    float f[8];
#pragma unroll
    for (int v = 0; v < 8; ++v) {
      int w = (int)((q >> (4 * v)) & 15u);
      f[v] = (float)(w - z) * s;
    }
    uint4 pk;
    pk.x = bf16pk(f[0], f[1]);
    pk.y = bf16pk(f[2], f[3]);
    pk.z = bf16pk(f[4], f[5]);
    pk.w = bf16pk(f[6], f[7]);
    int slot = k8 ^ (n & 7);
    *(uint4*)(&img[(n * 8 + slot) * 4]) = pk;
  }
  __syncthreads();
  uint32_t* tileOut = wImg + (size_t)(nt * 64 + kt) * 4096;
#pragma unroll
  for (int i = 0; i < 4; ++i) {
    int o = i * 256 + tid;
    *(uint4*)(tileOut + (size_t)o * 4) = *(const uint4*)(&img[o * 4]);
  }
}

// ---------------------------------------------------------------------------
// GEMM: 8-phase-style schedule. BM=128, BN=256, BK=64, 8 waves (2Mx4N),
// per-wave 64x64 (4x4 16x16x32 frags). 3 LDS buffers x 48KB (A 16K, B 32K),
// depth-2 prefetch, counted vmcnt(6) per tile boundary, raw s_barrier,
// setprio around MFMA clusters. grid = 256 blocks = 1/CU.
//
// vmcnt ledger (per wave, 6 load-insts per tile):
//   entry of tile t: tile t landed; tile t+1 outstanding (<=6).
//   phases 0..2 issue tile t+2's 6 loads (2/phase).
//   end of tile t: outstanding <= 12; vmcnt(6) -> tile t+1's 6 landed
//   (in-order retire), tile t+2's 6 still in flight. Never drains to 0.
// ---------------------------------------------------------------------------
__device__ __forceinline__ void glds16(const char* g, char* l) {
  __builtin_amdgcn_global_load_lds((__attribute__((address_space(1))) void*)g,
                                   (__attribute__((address_space(3))) void*)l, 16, 0, 0);
}
// stage one 16KB image (2 x 8KB chunks; 512 threads x 16B each)
__device__ __forceinline__ void stage16k(const char* src, char* dst, int tid, int wid) {
  glds16(src + tid * 16,        dst + wid * 1024);
  glds16(src + 8192 + tid * 16, dst + 8192 + wid * 1024);
}

__global__ void __launch_bounds__(512, 2) gemm_kernel(const uint32_t* __restrict__ xImg,
                                                      const uint32_t* __restrict__ wImg,
                                                      const float* __restrict__ bias,
                                                      float* __restrict__ out) {
  __shared__ uint4 ldsv[9216];     // 147456 B = 3 buffers x 48KB
  char* lds = (char*)ldsv;
  const int tid = threadIdx.x;
  const int lane = tid & 63, wid = tid >> 6;
  const int wr = wid >> 2, wc = wid & 3;          // 2M x 4N waves
  const int lr = lane & 15, lk = lane >> 4;
  const int bid = blockIdx.x;                     // 256 = 16 mb x 16 nbp
  const int nbp = bid & 15, mb = bid >> 4;

  f32x4 acc[4][4];
#pragma unroll
  for (int i = 0; i < 4; ++i)
#pragma unroll
    for (int j = 0; j < 4; ++j) acc[i][j] = f32x4{0.f, 0.f, 0.f, 0.f};

  const char* aT  = (const char*)xImg + (size_t)mb * (64 * 16384);
  const char* bT0 = (const char*)wImg + (size_t)(2 * nbp) * (64 * 16384);
  const char* bT1 = bT0 + (size_t)(64 * 16384);

  const int swz = (lr & 7) << 4;
  int aOff[4];
#pragma unroll
  for (int i = 0; i < 4; ++i) aOff[i] = (wr * 64 + i * 16 + lr) * 128;
  const int bBase = 16384 + (wc >> 1) * 16384 + ((wc & 1) * 64 + lr) * 128;
  const int kOff0 = (lk * 16) ^ swz;
  const int kOff1 = (64 + lk * 16) ^ swz;

  // prologue: stage tiles 0 (buf0) and 1 (buf1); 12 loads in flight
  stage16k(aT,           lds + 0,             tid, wid);
  stage16k(bT0,          lds + 16384,         tid, wid);
  stage16k(bT1,          lds + 32768,         tid, wid);
  stage16k(aT + 16384,   lds + 49152,         tid, wid);
  stage16k(bT0 + 16384,  lds + 49152 + 16384, tid, wid);
  stage16k(bT1 + 16384,  lds + 49152 + 32768, tid, wid);
  asm volatile("s_waitcnt vmcnt(6)" ::: "memory");   // tile 0 landed
  __builtin_amdgcn_sched_barrier(0);
  __builtin_amdgcn_s_barrier();

  int c = 0;
  for (int t = 0; t < 64; ++t) {
    char* buf = lds + c * 49152;
    const int bn = (c == 0) ? 2 : c - 1;            // (c+2)%3
    char* nbuf = lds + bn * 49152;
    const size_t toff = (size_t)((t + 2) & 63) * 16384;

    short8 af[4][2], bf0, bf1;

    // ---- phase 0: j=0 (reads all A frags + bf[0]) ----
#pragma unroll
    for (int i = 0; i < 4; ++i) {
      af[i][0] = *(const short8*)(buf + aOff[i] + kOff0);
      af[i][1] = *(const short8*)(buf + aOff[i] + kOff1);
    }
    bf0 = *(const short8*)(buf + bBase + 0 * 2048 + kOff0);
    bf1 = *(const short8*)(buf + bBase + 0 * 2048 + kOff1);
    stage16k(aT + toff, nbuf, tid, wid);
    __builtin_amdgcn_s_barrier();
    __builtin_amdgcn_s_setprio(1);
#pragma unroll
    for (int i = 0; i < 4; ++i)
      acc[i][0] = __builtin_amdgcn_mfma_f32_16x16x32_bf16(af[i][0], bf0, acc[i][0], 0, 0, 0);
#pragma unroll
    for (int i = 0; i < 4; ++i)
      acc[i][0] = __builtin_amdgcn_mfma_f32_16x16x32_bf16(af[i][1], bf1, acc[i][0], 0, 0, 0);
    __builtin_amdgcn_s_setprio(0);
    __builtin_amdgcn_s_barrier();

    // ---- phase 1: j=1 ----
    bf0 = *(const short8*)(buf + bBase + 1 * 2048 + kOff0);
    bf1 = *(const short8*)(buf + bBase + 1 * 2048 + kOff1);
    stage16k(bT0 + toff, nbuf + 16384, tid, wid);
    __builtin_amdgcn_s_barrier();
    __builtin_amdgcn_s_setprio(1);
#pragma unroll
    for (int i = 0; i < 4; ++i)
      acc[i][1] = __builtin_amdgcn_mfma_f32_16x16x32_bf16(af[i][0], bf0, acc[i][1], 0, 0, 0);
#pragma unroll
    for (int i = 0; i < 4; ++i)
      acc[i][1] = __builtin_amdgcn_mfma_f32_16x16x32_bf16(af[i][1], bf1, acc[i][1], 0, 0, 0);
    __builtin_amdgcn_s_setprio(0);
    __builtin_amdgcn_s_barrier();

    // ---- phase 2: j=2 ----
    bf0 = *(const short8*)(buf + bBase + 2 * 2048 + kOff0);
    bf1 = *(const short8*)(buf + bBase + 2 * 2048 + kOff1);
    stage16k(bT1 + toff, nbuf + 32768, tid, wid);
    __builtin_amdgcn_s_barrier();
    __builtin_amdgcn_s_setprio(1);
#pragma unroll
    for (int i = 0; i < 4; ++i)
      acc[i][2] = __builtin_amdgcn_mfma_f32_16x16x32_bf16(af[i][0], bf0, acc[i][2], 0, 0, 0);
#pragma unroll
    for (int i = 0; i < 4; ++i)
      acc[i][2] = __builtin_amdgcn_mfma_f32_16x16x32_bf16(af[i][1], bf1, acc[i][2], 0, 0, 0);
    __builtin_amdgcn_s_setprio(0);
    __builtin_amdgcn_s_barrier();

    // ---- phase 3: j=3 (no stage; tile-boundary counted wait) ----
    bf0 = *(const short8*)(buf + bBase + 3 * 2048 + kOff0);
    bf1 = *(const short8*)(buf + bBase + 3 * 2048 + kOff1);
    __builtin_amdgcn_s_barrier();
    __builtin_amdgcn_s_setprio(1);
#pragma unroll
    for (int i = 0; i < 4; ++i)
      acc[i][3] = __builtin_amdgcn_mfma_f32_16x16x32_bf16(af[i][0], bf0, acc[i][3], 0, 0, 0);
#pragma unroll
    for (int i = 0; i < 4; ++i)
      acc[i][3] = __builtin_amdgcn_mfma_f32_16x16x32_bf16(af[i][1], bf1, acc[i][3], 0, 0, 0);
    __builtin_amdgcn_s_setprio(0);
    asm volatile("s_waitcnt vmcnt(6)" ::: "memory");   // next tile landed; t+2 stays in flight
    __builtin_amdgcn_sched_barrier(0);
    __builtin_amdgcn_s_barrier();

    c = (c == 2) ? 0 : c + 1;
  }

  // epilogue: C/D mapping col=lane&15, row=(lane>>4)*4+reg (m89-verified)
  const int colBase = nbp * 256 + wc * 64 + lr;
  const int rowBase = mb * 128 + wr * 64 + lk * 4;
#pragma unroll
  for (int j = 0; j < 4; ++j) {
    int col = colBase + j * 16;
    float bj = bias[col];
#pragma unroll
    for (int i = 0; i < 4; ++i) {
      int row = rowBase + i * 16;
#pragma unroll
      for (int r = 0; r < 4; ++r) {
        out[(size_t)(row + r) * N_DIM + col] = acc[i][j][r] + bj;
      }
    }
  }
}

// ---------------------------------------------------------------------------
// Fallback (workspace too small): correct-but-slow fp32 tiled GEMM w/ fused dequant
// ---------------------------------------------------------------------------
__global__ void fallback_kernel(const float* __restrict__ x, const uint32_t* __restrict__ qweight,
                                const uint32_t* __restrict__ qzeros, const float* __restrict__ scales,
                                const float* __restrict__ bias, float* __restrict__ out) {
  __shared__ float xs[16][17];
  __shared__ float ws[16][17];
  int tx = threadIdx.x, ty = threadIdx.y;
  int col = blockIdx.x * 16 + tx;
  int row = blockIdx.y * 16 + ty;
  float acc = 0.f;
  for (int k0 = 0; k0 < K_DIM; k0 += 16) {
    xs[ty][tx] = x[(size_t)row * K_DIM + k0 + tx];
    int k = k0 + ty;
    int g = k >> 7;
    uint32_t q = qweight[(size_t)(k >> 3) * N_DIM + col];
    int w = (int)((q >> ((k & 7) * 4)) & 15u);
    uint32_t zq = qzeros[g * (N_DIM / 8) + (col >> 3)];
    int z = (int)((zq >> ((col & 7) * 4)) & 15u) + 1;
    ws[ty][tx] = (float)(w - z) * scales[g * N_DIM + col];
    __syncthreads();
#pragma unroll
    for (int kk = 0; kk < 16; ++kk) acc += xs[ty][kk] * ws[kk][tx];
    __syncthreads();
  }
  out[(size_t)row * N_DIM + col] = acc + bias[col];
}

extern "C" void kernel_launch(void* const* d_in, const int* in_sizes, int n_in,
                              void* d_out, int out_size, void* d_ws, size_t ws_size,
                              hipStream_t stream) {
  const float* x = (const float*)d_in[0];
  const uint32_t* qweight = (const uint32_t*)d_in[1];
  const uint32_t* qzeros = (const uint32_t*)d_in[2];
  const float* scales = (const float*)d_in[3];
  // d_in[4] = g_idx (== arange(K)//128, folded into index math)
  const float* bias = (const float*)d_in[5];
  float* out = (float*)d_out;

  const size_t X_IMG_BYTES = (size_t)16 * 64 * 16384;   // 16.78 MB
  const size_t W_IMG_BYTES = (size_t)32 * 64 * 16384;   // 33.55 MB

  if (ws_size >= X_IMG_BYTES + W_IMG_BYTES) {
    uint32_t* xImg = (uint32_t*)d_ws;
    uint32_t* wImg = (uint32_t*)((char*)d_ws + X_IMG_BYTES);
    cvt_x_kernel<<<1024, 256, 0, stream>>>(x, xImg);
    deq_w_kernel<<<2048, 256, 0, stream>>>(qweight, qzeros, scales, wImg);
    gemm_kernel<<<256, 512, 0, stream>>>(xImg, wImg, bias, out);
  } else {
    fallback_kernel<<<dim3(N_DIM / 16, M_DIM / 16), dim3(16, 16), 0, stream>>>(
        x, qweight, qzeros, scales, bias, out);
  }
}